// Round 7
// baseline (297.645 us; speedup 1.0000x reference)
//
#include <hip/hip_runtime.h>
#include <stdint.h>

typedef __bf16 bf16_t;
typedef bf16_t bf16x8 __attribute__((ext_vector_type(8)));
typedef bf16_t bf16x4 __attribute__((ext_vector_type(4)));
typedef bf16_t bf16x2 __attribute__((ext_vector_type(2)));
typedef float f32x4 __attribute__((ext_vector_type(4)));
typedef float f32x16 __attribute__((ext_vector_type(16)));
typedef uint32_t u32x4 __attribute__((ext_vector_type(4)));

#define DEV __device__ __forceinline__

DEV void gload_lds16(const void* g, void* l) {
  __builtin_amdgcn_global_load_lds(
      (__attribute__((address_space(1))) void*)(g),
      (__attribute__((address_space(3))) void*)(l), 16, 0, 0);
}

// ---------------- convert kernels ----------------
__global__ __launch_bounds__(256) void cvt2_kernel(
    const float* __restrict__ x, const float* __restrict__ q,
    bf16_t* __restrict__ xb, bf16_t* __restrict__ qb) {
  const float* s = blockIdx.y ? q : x;
  bf16_t* d = blockIdx.y ? qb : xb;
  int i = blockIdx.x * 256 + threadIdx.x;
  if (i < 524288) {
    const float4* sp = (const float4*)s + (size_t)i * 2;
    float4 a = sp[0], b = sp[1];
    bf16x8 o;
    o[0] = (bf16_t)a.x; o[1] = (bf16_t)a.y; o[2] = (bf16_t)a.z; o[3] = (bf16_t)a.w;
    o[4] = (bf16_t)b.x; o[5] = (bf16_t)b.y; o[6] = (bf16_t)b.z; o[7] = (bf16_t)b.w;
    *(bf16x8*)(d + (size_t)i * 8) = o;
  }
}

__global__ __launch_bounds__(256) void cvtw_kernel(
    const float* __restrict__ Wq, const float* __restrict__ Wk,
    const float* __restrict__ Wv, const float* __restrict__ Wo,
    bf16_t* __restrict__ dst) {
  int y = blockIdx.y;
  const float* s = (y == 0) ? Wq : (y == 1) ? Wk : (y == 2) ? Wv : Wo;
  bf16_t* d = dst + (size_t)y * 262144;
  int i = blockIdx.x * 256 + threadIdx.x;
  if (i < 32768) {
    const float4* sp = (const float4*)s + (size_t)i * 2;
    float4 a = sp[0], b = sp[1];
    bf16x8 o;
    o[0] = (bf16_t)a.x; o[1] = (bf16_t)a.y; o[2] = (bf16_t)a.z; o[3] = (bf16_t)a.w;
    o[4] = (bf16_t)b.x; o[5] = (bf16_t)b.y; o[6] = (bf16_t)b.z; o[7] = (bf16_t)b.w;
    *(bf16x8*)(d + (size_t)i * 8) = o;
  }
}

// ---------------- GEMM core: C[128x128] = A[128xK] * W[128xK]^T ----------------
DEV void gemm_core(const bf16_t* __restrict__ A, const bf16_t* __restrict__ W,
                   char* smem, f32x4 (&acc)[4][4]) {
  const int tid = threadIdx.x;
  const int lane = tid & 63;
  const int wid = tid >> 6;
  const int wr = wid >> 1, wc = wid & 1;
  const int bx = blockIdx.x, by = blockIdx.y;

  uint32_t goffA[4], goffB[4], ldsoff[4];
#pragma unroll
  for (int c = 0; c < 4; ++c) {
    uint32_t o = (uint32_t)wid * 4096u + (uint32_t)c * 1024u + (uint32_t)lane * 16u;
    uint32_t row = o >> 7;
    uint32_t inner = (o & 127u) ^ ((row & 7u) << 4);
    goffA[c] = ((uint32_t)by * 128u + row) * 1024u + inner;
    goffB[c] = ((uint32_t)bx * 128u + row) * 1024u + inner;
    ldsoff[c] = o - (uint32_t)lane * 16u;
  }
  uint32_t offA[4][2], offB[4][2];
#pragma unroll
  for (int i = 0; i < 4; ++i)
#pragma unroll
    for (int kk = 0; kk < 2; ++kk) {
      uint32_t ra = (uint32_t)(wr * 64 + i * 16 + (lane & 15));
      offA[i][kk] = ra * 128u + (((uint32_t)kk * 64u + ((lane >> 4) * 16u)) ^ ((ra & 7u) << 4));
      uint32_t rb = (uint32_t)(wc * 64 + i * 16 + (lane & 15));
      offB[i][kk] = rb * 128u + (((uint32_t)kk * 64u + ((lane >> 4) * 16u)) ^ ((rb & 7u) << 4));
    }

  const char* Ab = (const char*)A;
  const char* Wb = (const char*)W;

#pragma unroll
  for (int c = 0; c < 4; ++c) {
    gload_lds16(Ab + goffA[c], smem + ldsoff[c]);
    gload_lds16(Wb + goffB[c], smem + 16384 + ldsoff[c]);
  }
  asm volatile("s_waitcnt vmcnt(0)" ::: "memory");
  __syncthreads();

#pragma unroll 1
  for (int kt = 0; kt < 8; ++kt) {
    const int buf = kt & 1;
    char* cur = smem + buf * 32768;
    if (kt < 7) {
      char* nxt = smem + (buf ^ 1) * 32768;
      uint32_t gk = (uint32_t)(kt + 1) * 128u;
#pragma unroll
      for (int c = 0; c < 4; ++c) {
        gload_lds16(Ab + goffA[c] + gk, nxt + ldsoff[c]);
        gload_lds16(Wb + goffB[c] + gk, nxt + 16384 + ldsoff[c]);
      }
    }
    bf16x8 af[4][2], bfr[4][2];
#pragma unroll
    for (int kk = 0; kk < 2; ++kk)
#pragma unroll
      for (int i = 0; i < 4; ++i) {
        af[i][kk] = *(const bf16x8*)(cur + offA[i][kk]);
        bfr[i][kk] = *(const bf16x8*)(cur + 16384 + offB[i][kk]);
      }
    __builtin_amdgcn_s_setprio(1);
#pragma unroll
    for (int kk = 0; kk < 2; ++kk)
#pragma unroll
      for (int mi = 0; mi < 4; ++mi)
#pragma unroll
        for (int nj = 0; nj < 4; ++nj)
          acc[mi][nj] = __builtin_amdgcn_mfma_f32_16x16x32_bf16(
              af[mi][kk], bfr[nj][kk], acc[mi][nj], 0, 0, 0);
    __builtin_amdgcn_s_setprio(0);
    asm volatile("s_waitcnt vmcnt(0)" ::: "memory");
    __syncthreads();
  }
}

// QKV projection. z=0 -> Q (pre-scaled by 0.125*log2e), z=1 -> K, z=2 -> V^T.
__global__ __launch_bounds__(256) void gemm_qkv_kernel(
    const bf16_t* __restrict__ xb, const bf16_t* __restrict__ qb,
    const bf16_t* __restrict__ Wb, const float* __restrict__ bq,
    const float* __restrict__ bk, const float* __restrict__ bv,
    bf16_t* __restrict__ Qh, bf16_t* __restrict__ Kh, bf16_t* __restrict__ VT) {
  __shared__ char smem[65536];
  const int z = blockIdx.z;
  const bf16_t* A = (z == 0) ? qb : xb;
  const bf16_t* W = Wb + (size_t)z * 262144;
  const float* bias = (z == 0) ? bq : (z == 1) ? bk : bv;

  f32x4 acc[4][4] = {};
  gemm_core(A, W, smem, acc);

  const int lane = threadIdx.x & 63, wid = threadIdx.x >> 6;
  const int wr = wid >> 1, wc = wid & 1;
  const int colbase = blockIdx.x * 128 + wc * 64 + (lane & 15);
  const int rowbase = blockIdx.y * 128 + wr * 64 + ((lane >> 4) << 2);

  if (z == 2) {
#pragma unroll
    for (int nj = 0; nj < 4; ++nj) {
      int c = colbase + nj * 16;
      float bb = bias[c];
      int h = c >> 6, d = c & 63;
#pragma unroll
      for (int mi = 0; mi < 4; ++mi) {
        int r0 = rowbase + mi * 16;
        int b = r0 >> 11, s0 = r0 & 2047;
        bf16x4 v;
#pragma unroll
        for (int rr = 0; rr < 4; ++rr) v[rr] = (bf16_t)(acc[mi][nj][rr] + bb);
        *(bf16x4*)(VT + ((size_t)((b << 3) | h) * 64 + d) * 2048 + s0) = v;
      }
    }
  } else {
    bf16_t* O = (z == 0) ? Qh : Kh;
    const float scl = (z == 0) ? 0.18033688f : 1.0f;  // 0.125 * log2(e)
#pragma unroll
    for (int nj = 0; nj < 4; ++nj) {
      int c = colbase + nj * 16;
      float bb = bias[c];
      int h = c >> 6, d = c & 63;
#pragma unroll
      for (int mi = 0; mi < 4; ++mi)
#pragma unroll
        for (int rr = 0; rr < 4; ++rr) {
          int r = rowbase + mi * 16 + rr;
          int b = r >> 11, s = r & 2047;
          O[((size_t)((b << 3) | h) * 2048 + s) * 64 + d] = (bf16_t)((acc[mi][nj][rr] + bb) * scl);
        }
    }
  }
}

// Output projection: out = ctx @ Wo^T + bo, f32 [8192][512]
__global__ __launch_bounds__(256) void gemm_out_kernel(
    const bf16_t* __restrict__ ctx, const bf16_t* __restrict__ Wo,
    const float* __restrict__ bo, float* __restrict__ out) {
  __shared__ char smem[65536];
  f32x4 acc[4][4] = {};
  gemm_core(ctx, Wo, smem, acc);

  const int lane = threadIdx.x & 63, wid = threadIdx.x >> 6;
  const int wr = wid >> 1, wc = wid & 1;
  const int colbase = blockIdx.x * 128 + wc * 64 + (lane & 15);
  const int rowbase = blockIdx.y * 128 + wr * 64 + ((lane >> 4) << 2);
#pragma unroll
  for (int nj = 0; nj < 4; ++nj) {
    int c = colbase + nj * 16;
    float bb = bo[c];
#pragma unroll
    for (int mi = 0; mi < 4; ++mi)
#pragma unroll
      for (int rr = 0; rr < 4; ++rr) {
        int r = rowbase + mi * 16 + rr;
        out[(size_t)r * 512 + c] = acc[mi][nj][rr] + bb;
      }
  }
}

// ------------- flash attention, split-KV x2, in-register softmax -------------
// grid (16 qt, 32 bh, 2 sp), 4 waves x 32 q-rows, 16 KV tiles per block.
// Swapped 32x32 QK^T; unnormalized O partials (bf16) + (m,l) f32 per q-row;
// combine_kernel merges the two splits exactly.
__global__ __launch_bounds__(256, 4) void attn_kernel(
    const bf16_t* __restrict__ Qh, const bf16_t* __restrict__ Kh,
    const bf16_t* __restrict__ VT, bf16_t* __restrict__ Opart,
    float2* __restrict__ ml) {
  __shared__ char smem[32768];
  char* Kb = smem;            // 2 x 8KB: K tile [64 kv][128B d], swizzled
  char* Vb = smem + 16384;    // 2 x 8KB: V^T tile [64 d][128B kv], swizzled
  const int tid = threadIdx.x, lane = tid & 63, wid = tid >> 6;
  const int l31 = lane & 31, h = lane >> 5;
  const int qt = blockIdx.x, bh = blockIdx.y, sp = blockIdx.z;

  const char* Kbase = (const char*)Kh + (size_t)bh * 262144 + (size_t)sp * 131072;
  const char* Vbase = (const char*)VT + (size_t)bh * 262144 + (size_t)sp * 2048;
  const char* Qbase = (const char*)Qh + (size_t)bh * 262144;

  // Q fragments (B-operand of swapped QK^T): col=q=lane&31, k=d
  const int qrow = qt * 128 + wid * 32 + l31;
  bf16x8 qf[4];
#pragma unroll
  for (int ks = 0; ks < 4; ++ks)
    qf[ks] = *(const bf16x8*)(Qbase + (size_t)qrow * 128 + ks * 32 + h * 16);

  // staging offsets
  uint32_t kgo[2], vgo[2], lo[2];
#pragma unroll
  for (int c = 0; c < 2; ++c) {
    uint32_t o = (uint32_t)c * 4096u + (uint32_t)wid * 1024u + (uint32_t)lane * 16u;
    uint32_t row = o >> 7;
    uint32_t inner = (o & 127u) ^ ((row & 7u) << 4);
    kgo[c] = row * 128u + inner;   // + t*8192 (K row stride 128B)
    vgo[c] = row * 4096u + inner;  // + t*128  (VT row stride 4096B)
    lo[c] = o - (uint32_t)lane * 16u;
  }

  // fragment read offsets
  const uint32_t swz = (uint32_t)(l31 & 7) << 4;
  uint32_t fbase[2], fcol[4];
#pragma unroll
  for (int c = 0; c < 2; ++c) fbase[c] = (uint32_t)(32 * c + l31) * 128u;
#pragma unroll
  for (int ks = 0; ks < 4; ++ks) fcol[ks] = ((uint32_t)(ks * 32 + h * 16)) ^ swz;

  f32x16 oacc[2] = {};
  float m_run = -1.0e30f, l_part = 0.f;

  // prologue: stage tile 0 into buf 0
#pragma unroll
  for (int c = 0; c < 2; ++c) {
    gload_lds16(Kbase + kgo[c], Kb + lo[c]);
    gload_lds16(Vbase + vgo[c], Vb + lo[c]);
  }
  asm volatile("s_waitcnt vmcnt(0)" ::: "memory");
  __syncthreads();

#pragma unroll 1
  for (int t = 0; t < 16; ++t) {
    const uint32_t cur = ((uint32_t)t & 1u) << 13;
    if (t < 15) {
      const uint32_t nxt = cur ^ 8192u;
      const char* Kn = Kbase + (size_t)(t + 1) * 8192;
      const char* Vn = Vbase + (size_t)(t + 1) * 128;
#pragma unroll
      for (int c = 0; c < 2; ++c) {
        gload_lds16(Kn + kgo[c], Kb + nxt + lo[c]);
        gload_lds16(Vn + vgo[c], Vb + nxt + lo[c]);
      }
    }

    // S^T = mfma(K, Q): sT[c][reg] = S[q=l31][kv=32c+(reg&3)+8(reg>>2)+4h]
    f32x16 sT[2] = {};
#pragma unroll
    for (int c = 0; c < 2; ++c) {
      __builtin_amdgcn_s_setprio(1);
#pragma unroll
      for (int ks = 0; ks < 4; ++ks) {
        bf16x8 kf = *(const bf16x8*)(Kb + cur + fbase[c] + fcol[ks]);
        sT[c] = __builtin_amdgcn_mfma_f32_32x32x16_bf16(kf, qf[ks], sT[c], 0, 0, 0);
      }
      __builtin_amdgcn_s_setprio(0);
    }

    // P = exp2(S - m_run) with stale max; defer-check on the P-sum (tree sum)
    uint32_t cw[2][8];
    float la0 = 0.f, la1 = 0.f, la2 = 0.f, la3 = 0.f;
#pragma unroll
    for (int c = 0; c < 2; ++c)
#pragma unroll
      for (int w = 0; w < 8; ++w) {
        float p0 = __builtin_exp2f(sT[c][2 * w] - m_run);
        float p1 = __builtin_exp2f(sT[c][2 * w + 1] - m_run);
        if ((w & 3) == 0) la0 += p0 + p1;
        else if ((w & 3) == 1) la1 += p0 + p1;
        else if ((w & 3) == 2) la2 += p0 + p1;
        else la3 += p0 + p1;
        bf16x2 tp; tp[0] = (bf16_t)p0; tp[1] = (bf16_t)p1;
        cw[c][w] = __builtin_bit_cast(uint32_t, tp);
      }
    float ladd = (la0 + la1) + (la2 + la3);
    if (!__all(ladd <= 16384.0f)) {  // slow path: tile 0 + rare max growth
      float mx = sT[0][0];
#pragma unroll
      for (int c = 0; c < 2; ++c)
#pragma unroll
        for (int r = 0; r < 16; ++r) mx = fmaxf(mx, sT[c][r]);
      mx = fmaxf(mx, __shfl_xor(mx, 32));
      float mnew = fmaxf(m_run, mx);
      float sc = __builtin_exp2f(m_run - mnew);
      l_part *= sc;
#pragma unroll
      for (int r = 0; r < 16; ++r) { oacc[0][r] *= sc; oacc[1][r] *= sc; }
      m_run = mnew;
      la0 = la1 = la2 = la3 = 0.f;
#pragma unroll
      for (int c = 0; c < 2; ++c)
#pragma unroll
        for (int w = 0; w < 8; ++w) {
          float p0 = __builtin_exp2f(sT[c][2 * w] - m_run);
          float p1 = __builtin_exp2f(sT[c][2 * w + 1] - m_run);
          if ((w & 3) == 0) la0 += p0 + p1;
          else if ((w & 3) == 1) la1 += p0 + p1;
          else if ((w & 3) == 2) la2 += p0 + p1;
          else la3 += p0 + p1;
          bf16x2 tp; tp[0] = (bf16_t)p0; tp[1] = (bf16_t)p1;
          cw[c][w] = __builtin_bit_cast(uint32_t, tp);
        }
      ladd = (la0 + la1) + (la2 + la3);
    }
    l_part += ladd;

    // exchange: build P^T B-frags pa[s]: k=kv=16s+8h+{0..7} for own q col.
    bf16x8 pa[4];
#pragma unroll
    for (int s = 0; s < 4; ++s) {
      const int c = s >> 1, spp = s & 1;
      uint32_t w0 = cw[c][4 * spp + 0], w1 = cw[c][4 * spp + 1];
      uint32_t w2 = cw[c][4 * spp + 2], w3 = cw[c][4 * spp + 3];
      uint32_t sx0 = (uint32_t)__shfl_xor((int)w0, 32);
      uint32_t sx1 = (uint32_t)__shfl_xor((int)w1, 32);
      uint32_t sx2 = (uint32_t)__shfl_xor((int)w2, 32);
      uint32_t sx3 = (uint32_t)__shfl_xor((int)w3, 32);
      u32x4 ta;
      ta[0] = h ? sx2 : w0;
      ta[1] = h ? sx3 : w1;
      ta[2] = h ? w2 : sx0;
      ta[3] = h ? w3 : sx1;
      pa[s] = __builtin_bit_cast(bf16x8, ta);
    }

    // O^T += mfma(V^T, P^T): oacc[dc] col=q, row d=32dc+(reg&3)+8(reg>>2)+4h
#pragma unroll
    for (int dc = 0; dc < 2; ++dc) {
      __builtin_amdgcn_s_setprio(1);
#pragma unroll
      for (int ks = 0; ks < 4; ++ks) {
        bf16x8 vf = *(const bf16x8*)(Vb + cur + fbase[dc] + fcol[ks]);
        oacc[dc] = __builtin_amdgcn_mfma_f32_32x32x16_bf16(vf, pa[ks], oacc[dc], 0, 0, 0);
      }
      __builtin_amdgcn_s_setprio(0);
    }

    asm volatile("s_waitcnt vmcnt(0)" ::: "memory");
    __syncthreads();
  }

  // epilogue: write unnormalized O partial (bf16) + (m, l) f32 per q-row
  float l = l_part + __shfl_xor(l_part, 32);
  const size_t prow = (size_t)sp * 65536 + (size_t)bh * 2048 + qrow;
  if (h == 0) ml[prow] = make_float2(m_run, l);
  bf16_t* orow = Opart + prow * 64;
#pragma unroll
  for (int dc = 0; dc < 2; ++dc)
#pragma unroll
    for (int m = 0; m < 4; ++m) {
      bf16x4 v;
#pragma unroll
      for (int r = 0; r < 4; ++r) v[r] = (bf16_t)(oacc[dc][4 * m + r]);
      *(bf16x4*)(orow + dc * 32 + m * 8 + h * 4) = v;
    }
}

// Combine the two KV splits: ctx = (a0*O0 + a1*O1) / (a0*l0 + a1*l1)
__global__ __launch_bounds__(256) void combine_kernel(
    const bf16_t* __restrict__ Opart, const float2* __restrict__ ml,
    bf16_t* __restrict__ ctx) {
  int g = blockIdx.x * 256 + threadIdx.x;  // 524288 threads: 65536 rows x 8
  int row = g >> 3, d0 = (g & 7) * 8;
  float2 ml0 = ml[row], ml1 = ml[row + 65536];
  float mmax = fmaxf(ml0.x, ml1.x);
  float a0 = __builtin_exp2f(ml0.x - mmax);
  float a1 = __builtin_exp2f(ml1.x - mmax);
  float inv = 1.0f / (a0 * ml0.y + a1 * ml1.y);
  float s0 = a0 * inv, s1 = a1 * inv;
  bf16x8 o0 = *(const bf16x8*)(Opart + (size_t)row * 64 + d0);
  bf16x8 o1 = *(const bf16x8*)(Opart + (size_t)(row + 65536) * 64 + d0);
  bf16x8 o;
#pragma unroll
  for (int i = 0; i < 8; ++i) o[i] = (bf16_t)((float)o0[i] * s0 + (float)o1[i] * s1);
  int bh = row >> 11, qr = row & 2047;
  int b = bh >> 3, hh = bh & 7;
  *(bf16x8*)(ctx + ((size_t)(b * 2048 + qr)) * 512 + hh * 64 + d0) = o;
}

extern "C" void kernel_launch(void* const* d_in, const int* in_sizes, int n_in,
                              void* d_out, int out_size, void* d_ws, size_t ws_size,
                              hipStream_t stream) {
  const float* x  = (const float*)d_in[0];
  const float* q  = (const float*)d_in[1];
  const float* Wq = (const float*)d_in[2];
  const float* bq = (const float*)d_in[3];
  const float* Wk = (const float*)d_in[4];
  const float* bk = (const float*)d_in[5];
  const float* Wv = (const float*)d_in[6];
  const float* bv = (const float*)d_in[7];
  const float* Wo = (const float*)d_in[8];
  const float* bo = (const float*)d_in[9];

  char* ws = (char*)d_ws;
  bf16_t* xb    = (bf16_t*)(ws + 0);          // 8 MB
  bf16_t* qb    = (bf16_t*)(ws + 8388608);    // 8 MB
  bf16_t* Wb    = (bf16_t*)(ws + 16777216);   // 4 x 512KB
  bf16_t* Qh    = (bf16_t*)(ws + 18874368);   // 8 MB [32][2048][64]
  bf16_t* Kh    = (bf16_t*)(ws + 27262976);   // 8 MB [32][2048][64]
  bf16_t* VT    = (bf16_t*)(ws + 35651584);   // 8 MB [32][64][2048]
  bf16_t* ctx   = (bf16_t*)(ws + 44040192);   // 8 MB
  bf16_t* Opart = (bf16_t*)(ws + 52428800);   // 16 MB [2][32][2048][64]
  float2* mlb   = (float2*)(ws + 69206016);   // 1 MB  [2][32][2048]

  cvt2_kernel<<<dim3(2048, 2), 256, 0, stream>>>(x, q, xb, qb);
  cvtw_kernel<<<dim3(128, 4), 256, 0, stream>>>(Wq, Wk, Wv, Wo, Wb);
  gemm_qkv_kernel<<<dim3(4, 64, 3), 256, 0, stream>>>(xb, qb, Wb, bq, bk, bv, Qh, Kh, VT);
  attn_kernel<<<dim3(16, 32, 2), 256, 0, stream>>>(Qh, Kh, VT, Opart, mlb);
  combine_kernel<<<2048, 256, 0, stream>>>(Opart, mlb, ctx);
  gemm_out_kernel<<<dim3(4, 64), 256, 0, stream>>>(ctx, Wb + 3 * 262144, bo, (float*)d_out);
}

// Round 8
// 138.984 us; speedup vs baseline: 2.1416x; 2.1416x over previous
//
#include <hip/hip_runtime.h>
#include <stdint.h>

typedef __bf16 bf16_t;
typedef bf16_t bf16x8 __attribute__((ext_vector_type(8)));
typedef bf16_t bf16x4 __attribute__((ext_vector_type(4)));
typedef bf16_t bf16x2 __attribute__((ext_vector_type(2)));
typedef float f32x4 __attribute__((ext_vector_type(4)));
typedef float f32x16 __attribute__((ext_vector_type(16)));
typedef uint32_t u32x4 __attribute__((ext_vector_type(4)));

#define DEV __device__ __forceinline__

DEV void gload_lds16(const void* g, void* l) {
  __builtin_amdgcn_global_load_lds(
      (__attribute__((address_space(1))) void*)(g),
      (__attribute__((address_space(3))) void*)(l), 16, 0, 0);
}

// ---------------- convert kernels ----------------
__global__ __launch_bounds__(256) void cvt2_kernel(
    const float* __restrict__ x, const float* __restrict__ q,
    bf16_t* __restrict__ xb, bf16_t* __restrict__ qb) {
  const float* s = blockIdx.y ? q : x;
  bf16_t* d = blockIdx.y ? qb : xb;
  int i = blockIdx.x * 256 + threadIdx.x;
  if (i < 524288) {
    const float4* sp = (const float4*)s + (size_t)i * 2;
    float4 a = sp[0], b = sp[1];
    bf16x8 o;
    o[0] = (bf16_t)a.x; o[1] = (bf16_t)a.y; o[2] = (bf16_t)a.z; o[3] = (bf16_t)a.w;
    o[4] = (bf16_t)b.x; o[5] = (bf16_t)b.y; o[6] = (bf16_t)b.z; o[7] = (bf16_t)b.w;
    *(bf16x8*)(d + (size_t)i * 8) = o;
  }
}

__global__ __launch_bounds__(256) void cvtw_kernel(
    const float* __restrict__ Wq, const float* __restrict__ Wk,
    const float* __restrict__ Wv, const float* __restrict__ Wo,
    bf16_t* __restrict__ dst) {
  int y = blockIdx.y;
  const float* s = (y == 0) ? Wq : (y == 1) ? Wk : (y == 2) ? Wv : Wo;
  bf16_t* d = dst + (size_t)y * 262144;
  int i = blockIdx.x * 256 + threadIdx.x;
  if (i < 32768) {
    const float4* sp = (const float4*)s + (size_t)i * 2;
    float4 a = sp[0], b = sp[1];
    bf16x8 o;
    o[0] = (bf16_t)a.x; o[1] = (bf16_t)a.y; o[2] = (bf16_t)a.z; o[3] = (bf16_t)a.w;
    o[4] = (bf16_t)b.x; o[5] = (bf16_t)b.y; o[6] = (bf16_t)b.z; o[7] = (bf16_t)b.w;
    *(bf16x8*)(d + (size_t)i * 8) = o;
  }
}

// ---------------- GEMM core: C[128x128] = A[128xK] * W[128xK]^T ----------------
DEV void gemm_core(const bf16_t* __restrict__ A, const bf16_t* __restrict__ W,
                   char* smem, f32x4 (&acc)[4][4]) {
  const int tid = threadIdx.x;
  const int lane = tid & 63;
  const int wid = tid >> 6;
  const int wr = wid >> 1, wc = wid & 1;
  const int bx = blockIdx.x, by = blockIdx.y;

  uint32_t goffA[4], goffB[4], ldsoff[4];
#pragma unroll
  for (int c = 0; c < 4; ++c) {
    uint32_t o = (uint32_t)wid * 4096u + (uint32_t)c * 1024u + (uint32_t)lane * 16u;
    uint32_t row = o >> 7;
    uint32_t inner = (o & 127u) ^ ((row & 7u) << 4);
    goffA[c] = ((uint32_t)by * 128u + row) * 1024u + inner;
    goffB[c] = ((uint32_t)bx * 128u + row) * 1024u + inner;
    ldsoff[c] = o - (uint32_t)lane * 16u;
  }
  uint32_t offA[4][2], offB[4][2];
#pragma unroll
  for (int i = 0; i < 4; ++i)
#pragma unroll
    for (int kk = 0; kk < 2; ++kk) {
      uint32_t ra = (uint32_t)(wr * 64 + i * 16 + (lane & 15));
      offA[i][kk] = ra * 128u + (((uint32_t)kk * 64u + ((lane >> 4) * 16u)) ^ ((ra & 7u) << 4));
      uint32_t rb = (uint32_t)(wc * 64 + i * 16 + (lane & 15));
      offB[i][kk] = rb * 128u + (((uint32_t)kk * 64u + ((lane >> 4) * 16u)) ^ ((rb & 7u) << 4));
    }

  const char* Ab = (const char*)A;
  const char* Wb = (const char*)W;

#pragma unroll
  for (int c = 0; c < 4; ++c) {
    gload_lds16(Ab + goffA[c], smem + ldsoff[c]);
    gload_lds16(Wb + goffB[c], smem + 16384 + ldsoff[c]);
  }
  asm volatile("s_waitcnt vmcnt(0)" ::: "memory");
  __syncthreads();

#pragma unroll 1
  for (int kt = 0; kt < 8; ++kt) {
    const int buf = kt & 1;
    char* cur = smem + buf * 32768;
    if (kt < 7) {
      char* nxt = smem + (buf ^ 1) * 32768;
      uint32_t gk = (uint32_t)(kt + 1) * 128u;
#pragma unroll
      for (int c = 0; c < 4; ++c) {
        gload_lds16(Ab + goffA[c] + gk, nxt + ldsoff[c]);
        gload_lds16(Wb + goffB[c] + gk, nxt + 16384 + ldsoff[c]);
      }
    }
    bf16x8 af[4][2], bfr[4][2];
#pragma unroll
    for (int kk = 0; kk < 2; ++kk)
#pragma unroll
      for (int i = 0; i < 4; ++i) {
        af[i][kk] = *(const bf16x8*)(cur + offA[i][kk]);
        bfr[i][kk] = *(const bf16x8*)(cur + 16384 + offB[i][kk]);
      }
    __builtin_amdgcn_s_setprio(1);
#pragma unroll
    for (int kk = 0; kk < 2; ++kk)
#pragma unroll
      for (int mi = 0; mi < 4; ++mi)
#pragma unroll
        for (int nj = 0; nj < 4; ++nj)
          acc[mi][nj] = __builtin_amdgcn_mfma_f32_16x16x32_bf16(
              af[mi][kk], bfr[nj][kk], acc[mi][nj], 0, 0, 0);
    __builtin_amdgcn_s_setprio(0);
    asm volatile("s_waitcnt vmcnt(0)" ::: "memory");
    __syncthreads();
  }
}

// QKV projection. z=0 -> Q (pre-scaled by 0.125*log2e), z=1 -> K, z=2 -> V^T.
__global__ __launch_bounds__(256) void gemm_qkv_kernel(
    const bf16_t* __restrict__ xb, const bf16_t* __restrict__ qb,
    const bf16_t* __restrict__ Wb, const float* __restrict__ bq,
    const float* __restrict__ bk, const float* __restrict__ bv,
    bf16_t* __restrict__ Qh, bf16_t* __restrict__ Kh, bf16_t* __restrict__ VT) {
  __shared__ char smem[65536];
  const int z = blockIdx.z;
  const bf16_t* A = (z == 0) ? qb : xb;
  const bf16_t* W = Wb + (size_t)z * 262144;
  const float* bias = (z == 0) ? bq : (z == 1) ? bk : bv;

  f32x4 acc[4][4] = {};
  gemm_core(A, W, smem, acc);

  const int lane = threadIdx.x & 63, wid = threadIdx.x >> 6;
  const int wr = wid >> 1, wc = wid & 1;
  const int colbase = blockIdx.x * 128 + wc * 64 + (lane & 15);
  const int rowbase = blockIdx.y * 128 + wr * 64 + ((lane >> 4) << 2);

  if (z == 2) {
#pragma unroll
    for (int nj = 0; nj < 4; ++nj) {
      int c = colbase + nj * 16;
      float bb = bias[c];
      int h = c >> 6, d = c & 63;
#pragma unroll
      for (int mi = 0; mi < 4; ++mi) {
        int r0 = rowbase + mi * 16;
        int b = r0 >> 11, s0 = r0 & 2047;
        bf16x4 v;
#pragma unroll
        for (int rr = 0; rr < 4; ++rr) v[rr] = (bf16_t)(acc[mi][nj][rr] + bb);
        *(bf16x4*)(VT + ((size_t)((b << 3) | h) * 64 + d) * 2048 + s0) = v;
      }
    }
  } else {
    bf16_t* O = (z == 0) ? Qh : Kh;
    const float scl = (z == 0) ? 0.18033688f : 1.0f;  // 0.125 * log2(e)
#pragma unroll
    for (int nj = 0; nj < 4; ++nj) {
      int c = colbase + nj * 16;
      float bb = bias[c];
      int h = c >> 6, d = c & 63;
#pragma unroll
      for (int mi = 0; mi < 4; ++mi)
#pragma unroll
        for (int rr = 0; rr < 4; ++rr) {
          int r = rowbase + mi * 16 + rr;
          int b = r >> 11, s = r & 2047;
          O[((size_t)((b << 3) | h) * 2048 + s) * 64 + d] = (bf16_t)((acc[mi][nj][rr] + bb) * scl);
        }
    }
  }
}

// Output projection: out = ctx @ Wo^T + bo, f32 [8192][512]
__global__ __launch_bounds__(256) void gemm_out_kernel(
    const bf16_t* __restrict__ ctx, const bf16_t* __restrict__ Wo,
    const float* __restrict__ bo, float* __restrict__ out) {
  __shared__ char smem[65536];
  f32x4 acc[4][4] = {};
  gemm_core(ctx, Wo, smem, acc);

  const int lane = threadIdx.x & 63, wid = threadIdx.x >> 6;
  const int wr = wid >> 1, wc = wid & 1;
  const int colbase = blockIdx.x * 128 + wc * 64 + (lane & 15);
  const int rowbase = blockIdx.y * 128 + wr * 64 + ((lane >> 4) << 2);
#pragma unroll
  for (int nj = 0; nj < 4; ++nj) {
    int c = colbase + nj * 16;
    float bb = bo[c];
#pragma unroll
    for (int mi = 0; mi < 4; ++mi)
#pragma unroll
      for (int rr = 0; rr < 4; ++rr) {
        int r = rowbase + mi * 16 + rr;
        out[(size_t)r * 512 + c] = acc[mi][nj][rr] + bb;
      }
  }
}

// ------------- flash attention: KVBLK=128, swapped 32x32, in-reg softmax -----
// grid (16 qt, 32 bh), 4 waves x 32 q-rows, 16 iterations of 128 kv.
// Halved barriers/drains per kv vs KVBLK=64; 4 independent QK chains for ILP.
// K tile [128 kv][128B] swizzle (row&7)<<4 (4-way read floor);
// V^T tile [64 d][256B kv] swizzle (row&15)<<4 -> conflict-free V reads.
__global__ __launch_bounds__(256, 2) void attn_kernel(
    const bf16_t* __restrict__ Qh, const bf16_t* __restrict__ Kh,
    const bf16_t* __restrict__ VT, bf16_t* __restrict__ ctx) {
  __shared__ char smem[65536];  // 2 bufs: K 16KB @ b*16384, V 16KB @ 32768+b*16384
  const int tid = threadIdx.x, lane = tid & 63, wid = tid >> 6;
  const int l31 = lane & 31, h = lane >> 5;
  const int qt = blockIdx.x, bh = blockIdx.y;

  const char* Kbase = (const char*)Kh + (size_t)bh * 262144;  // [2048][128B]
  const char* Vbase = (const char*)VT + (size_t)bh * 262144;  // [64][4096B]
  const char* Qbase = (const char*)Qh + (size_t)bh * 262144;

  // Q fragments (B-operand of swapped QK^T): col=q=lane&31, k=d
  const int qrow = qt * 128 + wid * 32 + l31;
  bf16x8 qf[4];
#pragma unroll
  for (int ks = 0; ks < 4; ++ks)
    qf[ks] = *(const bf16x8*)(Qbase + (size_t)qrow * 128 + ks * 32 + h * 16);

  // staging offsets: 4 issues each for K (16KB) and V (16KB) per tile
  uint32_t kgo[4], vgo[4], lo[4];
#pragma unroll
  for (int c = 0; c < 4; ++c) {
    uint32_t o = (uint32_t)c * 4096u + (uint32_t)wid * 1024u + (uint32_t)lane * 16u;
    uint32_t krow = o >> 7;
    kgo[c] = krow * 128u + ((o & 127u) ^ ((krow & 7u) << 4));    // + t*16384
    uint32_t vrow = o >> 8;
    vgo[c] = vrow * 4096u + ((o & 255u) ^ ((vrow & 15u) << 4));  // + t*256
    lo[c] = o - (uint32_t)lane * 16u;
  }

  // K fragment read offsets: row = 32c + l31, col = (ks*32 + h*16) ^ swzK
  const uint32_t swzK = (uint32_t)(l31 & 7) << 4;
  uint32_t kcol[4];
#pragma unroll
  for (int ks = 0; ks < 4; ++ks) kcol[ks] = ((uint32_t)(ks * 32 + h * 16)) ^ swzK;
  // V fragment read offsets: row = 32dc + l31, col = (s*32 + h*16) ^ swzV
  const uint32_t swzV = (uint32_t)(l31 & 15) << 4;
  uint32_t vcol[8];
#pragma unroll
  for (int s = 0; s < 8; ++s) vcol[s] = ((uint32_t)(s * 32 + h * 16)) ^ swzV;

  f32x16 oacc[2] = {};
  float m_run = -1.0e30f, l_part = 0.f;

  // prologue: stage tile 0 into buf 0
#pragma unroll
  for (int c = 0; c < 4; ++c) {
    gload_lds16(Kbase + kgo[c], smem + lo[c]);
    gload_lds16(Vbase + vgo[c], smem + 32768 + lo[c]);
  }
  asm volatile("s_waitcnt vmcnt(0)" ::: "memory");
  __syncthreads();

#pragma unroll 1
  for (int t = 0; t < 16; ++t) {
    const uint32_t cur = ((uint32_t)t & 1u) * 16384u;
    char* Kc = smem + cur;
    char* Vc = smem + 32768 + cur;
    if (t < 15) {
      const uint32_t nxt = cur ^ 16384u;
      const char* Kn = Kbase + (size_t)(t + 1) * 16384;
      const char* Vn = Vbase + (size_t)(t + 1) * 256;
#pragma unroll
      for (int c = 0; c < 4; ++c) {
        gload_lds16(Kn + kgo[c], smem + nxt + lo[c]);
        gload_lds16(Vn + vgo[c], smem + 32768 + nxt + lo[c]);
      }
    }

    // S^T = mfma(K, Q): sT[c][reg] = S[q=l31][kv=32c+(reg&3)+8(reg>>2)+4h]
    f32x16 sT[4] = {};
    __builtin_amdgcn_s_setprio(1);
#pragma unroll
    for (int c = 0; c < 4; ++c)
#pragma unroll
      for (int ks = 0; ks < 4; ++ks) {
        bf16x8 kf = *(const bf16x8*)(Kc + (uint32_t)(32 * c + l31) * 128u + kcol[ks]);
        sT[c] = __builtin_amdgcn_mfma_f32_32x32x16_bf16(kf, qf[ks], sT[c], 0, 0, 0);
      }
    __builtin_amdgcn_s_setprio(0);

    // P = exp2(S - m_run) with stale max; defer-check on the P-sum (tree sum)
    uint32_t cw[4][8];
    float la0 = 0.f, la1 = 0.f, la2 = 0.f, la3 = 0.f;
#pragma unroll
    for (int c = 0; c < 4; ++c)
#pragma unroll
      for (int w = 0; w < 8; ++w) {
        float p0 = __builtin_exp2f(sT[c][2 * w] - m_run);
        float p1 = __builtin_exp2f(sT[c][2 * w + 1] - m_run);
        if ((w & 3) == 0) la0 += p0 + p1;
        else if ((w & 3) == 1) la1 += p0 + p1;
        else if ((w & 3) == 2) la2 += p0 + p1;
        else la3 += p0 + p1;
        bf16x2 tp; tp[0] = (bf16_t)p0; tp[1] = (bf16_t)p1;
        cw[c][w] = __builtin_bit_cast(uint32_t, tp);
      }
    float ladd = (la0 + la1) + (la2 + la3);
    if (!__all(ladd <= 16384.0f)) {  // slow path: tile 0 + rare max growth
      float mx = sT[0][0];
#pragma unroll
      for (int c = 0; c < 4; ++c)
#pragma unroll
        for (int r = 0; r < 16; ++r) mx = fmaxf(mx, sT[c][r]);
      mx = fmaxf(mx, __shfl_xor(mx, 32));
      float mnew = fmaxf(m_run, mx);
      float sc = __builtin_exp2f(m_run - mnew);
      l_part *= sc;
#pragma unroll
      for (int r = 0; r < 16; ++r) { oacc[0][r] *= sc; oacc[1][r] *= sc; }
      m_run = mnew;
      la0 = la1 = la2 = la3 = 0.f;
#pragma unroll
      for (int c = 0; c < 4; ++c)
#pragma unroll
        for (int w = 0; w < 8; ++w) {
          float p0 = __builtin_exp2f(sT[c][2 * w] - m_run);
          float p1 = __builtin_exp2f(sT[c][2 * w + 1] - m_run);
          if ((w & 3) == 0) la0 += p0 + p1;
          else if ((w & 3) == 1) la1 += p0 + p1;
          else if ((w & 3) == 2) la2 += p0 + p1;
          else la3 += p0 + p1;
          bf16x2 tp; tp[0] = (bf16_t)p0; tp[1] = (bf16_t)p1;
          cw[c][w] = __builtin_bit_cast(uint32_t, tp);
        }
      ladd = (la0 + la1) + (la2 + la3);
    }
    l_part += ladd;

    // exchange: build P^T B-frags pa[s] (s=2c+sp): k=kv=16s+8h+{0..7}
    bf16x8 pa[8];
#pragma unroll
    for (int s = 0; s < 8; ++s) {
      const int c = s >> 1, sp = s & 1;
      uint32_t w0 = cw[c][4 * sp + 0], w1 = cw[c][4 * sp + 1];
      uint32_t w2 = cw[c][4 * sp + 2], w3 = cw[c][4 * sp + 3];
      uint32_t sx0 = (uint32_t)__shfl_xor((int)w0, 32);
      uint32_t sx1 = (uint32_t)__shfl_xor((int)w1, 32);
      uint32_t sx2 = (uint32_t)__shfl_xor((int)w2, 32);
      uint32_t sx3 = (uint32_t)__shfl_xor((int)w3, 32);
      u32x4 ta;
      ta[0] = h ? sx2 : w0;
      ta[1] = h ? sx3 : w1;
      ta[2] = h ? w2 : sx0;
      ta[3] = h ? w3 : sx1;
      pa[s] = __builtin_bit_cast(bf16x8, ta);
    }

    // O^T += mfma(V^T, P^T): oacc[dc] col=q, row d=32dc+(reg&3)+8(reg>>2)+4h
    __builtin_amdgcn_s_setprio(1);
#pragma unroll
    for (int dc = 0; dc < 2; ++dc)
#pragma unroll
      for (int s = 0; s < 8; ++s) {
        bf16x8 vf = *(const bf16x8*)(Vc + (uint32_t)(32 * dc + l31) * 256u + vcol[s]);
        oacc[dc] = __builtin_amdgcn_mfma_f32_32x32x16_bf16(vf, pa[s], oacc[dc], 0, 0, 0);
      }
    __builtin_amdgcn_s_setprio(0);

    asm volatile("s_waitcnt vmcnt(0)" ::: "memory");
    __syncthreads();
  }

  // epilogue: full row sum = own + partner halves; normalize; write ctx
  float l = l_part + __shfl_xor(l_part, 32);
  float inv = 1.0f / l;
  const int b = bh >> 3, hh = bh & 7;
  bf16_t* crow = ctx + ((size_t)(b * 2048 + qrow)) * 512 + hh * 64;
#pragma unroll
  for (int dc = 0; dc < 2; ++dc)
#pragma unroll
    for (int m = 0; m < 4; ++m) {
      bf16x4 v;
#pragma unroll
      for (int r = 0; r < 4; ++r) v[r] = (bf16_t)(oacc[dc][4 * m + r] * inv);
      *(bf16x4*)(crow + dc * 32 + m * 8 + h * 4) = v;
    }
}

extern "C" void kernel_launch(void* const* d_in, const int* in_sizes, int n_in,
                              void* d_out, int out_size, void* d_ws, size_t ws_size,
                              hipStream_t stream) {
  const float* x  = (const float*)d_in[0];
  const float* q  = (const float*)d_in[1];
  const float* Wq = (const float*)d_in[2];
  const float* bq = (const float*)d_in[3];
  const float* Wk = (const float*)d_in[4];
  const float* bk = (const float*)d_in[5];
  const float* Wv = (const float*)d_in[6];
  const float* bv = (const float*)d_in[7];
  const float* Wo = (const float*)d_in[8];
  const float* bo = (const float*)d_in[9];

  char* ws = (char*)d_ws;
  bf16_t* xb  = (bf16_t*)(ws + 0);          // 8 MB
  bf16_t* qb  = (bf16_t*)(ws + 8388608);    // 8 MB
  bf16_t* Wb  = (bf16_t*)(ws + 16777216);   // 4 x 512KB
  bf16_t* Qh  = (bf16_t*)(ws + 18874368);   // 8 MB [32][2048][64]
  bf16_t* Kh  = (bf16_t*)(ws + 27262976);   // 8 MB [32][2048][64]
  bf16_t* VT  = (bf16_t*)(ws + 35651584);   // 8 MB [32][64][2048]
  bf16_t* ctx = (bf16_t*)(ws + 44040192);   // 8 MB

  cvt2_kernel<<<dim3(2048, 2), 256, 0, stream>>>(x, q, xb, qb);
  cvtw_kernel<<<dim3(128, 4), 256, 0, stream>>>(Wq, Wk, Wv, Wo, Wb);
  gemm_qkv_kernel<<<dim3(4, 64, 3), 256, 0, stream>>>(xb, qb, Wb, bq, bk, bv, Qh, Kh, VT);
  attn_kernel<<<dim3(16, 32), 256, 0, stream>>>(Qh, Kh, VT, ctx);
  gemm_out_kernel<<<dim3(4, 64), 256, 0, stream>>>(ctx, Wb + 3 * 262144, bo, (float*)d_out);
}

// Round 9
// 117.328 us; speedup vs baseline: 2.5369x; 1.1846x over previous
//
#include <hip/hip_runtime.h>
#include <stdint.h>

typedef __bf16 bf16_t;
typedef bf16_t bf16x8 __attribute__((ext_vector_type(8)));
typedef bf16_t bf16x4 __attribute__((ext_vector_type(4)));
typedef bf16_t bf16x2 __attribute__((ext_vector_type(2)));
typedef float f32x4 __attribute__((ext_vector_type(4)));
typedef float f32x16 __attribute__((ext_vector_type(16)));
typedef uint32_t u32x4 __attribute__((ext_vector_type(4)));

#define DEV __device__ __forceinline__

DEV void gload_lds16(const void* g, void* l) {
  __builtin_amdgcn_global_load_lds(
      (__attribute__((address_space(1))) void*)(g),
      (__attribute__((address_space(3))) void*)(l), 16, 0, 0);
}

// ---------------- fused convert kernel (x, q, 4 weights) ----------------
__global__ __launch_bounds__(256) void cvt_all_kernel(
    const float* __restrict__ x, const float* __restrict__ q,
    const float* __restrict__ Wq, const float* __restrict__ Wk,
    const float* __restrict__ Wv, const float* __restrict__ Wo,
    bf16_t* __restrict__ xb, bf16_t* __restrict__ qb, bf16_t* __restrict__ Wb) {
  const int y = blockIdx.y;
  int i = blockIdx.x * 256 + threadIdx.x;
  const float* s;
  bf16_t* d;
  if (y == 0) { s = x; d = xb; }
  else if (y == 1) { s = q; d = qb; }
  else {
    if (i >= 131072) return;  // 4 x 262144 elems / 8 per thread
    int widx = i >> 15;
    s = (widx == 0) ? Wq : (widx == 1) ? Wk : (widx == 2) ? Wv : Wo;
    d = Wb + (size_t)widx * 262144;
    i &= 32767;
  }
  const float4* sp = (const float4*)s + (size_t)i * 2;
  float4 a = sp[0], b = sp[1];
  bf16x8 o;
  o[0] = (bf16_t)a.x; o[1] = (bf16_t)a.y; o[2] = (bf16_t)a.z; o[3] = (bf16_t)a.w;
  o[4] = (bf16_t)b.x; o[5] = (bf16_t)b.y; o[6] = (bf16_t)b.z; o[7] = (bf16_t)b.w;
  *(bf16x8*)(d + (size_t)i * 8) = o;
}

// ---------------- GEMM core: C[128x128] = A[128xK] * W[128xK]^T ----------------
DEV void gemm_core(const bf16_t* __restrict__ A, const bf16_t* __restrict__ W,
                   char* smem, f32x4 (&acc)[4][4]) {
  const int tid = threadIdx.x;
  const int lane = tid & 63;
  const int wid = tid >> 6;
  const int wr = wid >> 1, wc = wid & 1;
  const int bx = blockIdx.x, by = blockIdx.y;

  uint32_t goffA[4], goffB[4], ldsoff[4];
#pragma unroll
  for (int c = 0; c < 4; ++c) {
    uint32_t o = (uint32_t)wid * 4096u + (uint32_t)c * 1024u + (uint32_t)lane * 16u;
    uint32_t row = o >> 7;
    uint32_t inner = (o & 127u) ^ ((row & 7u) << 4);
    goffA[c] = ((uint32_t)by * 128u + row) * 1024u + inner;
    goffB[c] = ((uint32_t)bx * 128u + row) * 1024u + inner;
    ldsoff[c] = o - (uint32_t)lane * 16u;
  }
  uint32_t offA[4][2], offB[4][2];
#pragma unroll
  for (int i = 0; i < 4; ++i)
#pragma unroll
    for (int kk = 0; kk < 2; ++kk) {
      uint32_t ra = (uint32_t)(wr * 64 + i * 16 + (lane & 15));
      offA[i][kk] = ra * 128u + (((uint32_t)kk * 64u + ((lane >> 4) * 16u)) ^ ((ra & 7u) << 4));
      uint32_t rb = (uint32_t)(wc * 64 + i * 16 + (lane & 15));
      offB[i][kk] = rb * 128u + (((uint32_t)kk * 64u + ((lane >> 4) * 16u)) ^ ((rb & 7u) << 4));
    }

  const char* Ab = (const char*)A;
  const char* Wb = (const char*)W;

#pragma unroll
  for (int c = 0; c < 4; ++c) {
    gload_lds16(Ab + goffA[c], smem + ldsoff[c]);
    gload_lds16(Wb + goffB[c], smem + 16384 + ldsoff[c]);
  }
  asm volatile("s_waitcnt vmcnt(0)" ::: "memory");
  __syncthreads();

#pragma unroll 1
  for (int kt = 0; kt < 8; ++kt) {
    const int buf = kt & 1;
    char* cur = smem + buf * 32768;
    if (kt < 7) {
      char* nxt = smem + (buf ^ 1) * 32768;
      uint32_t gk = (uint32_t)(kt + 1) * 128u;
#pragma unroll
      for (int c = 0; c < 4; ++c) {
        gload_lds16(Ab + goffA[c] + gk, nxt + ldsoff[c]);
        gload_lds16(Wb + goffB[c] + gk, nxt + 16384 + ldsoff[c]);
      }
    }
    bf16x8 af[4][2], bfr[4][2];
#pragma unroll
    for (int kk = 0; kk < 2; ++kk)
#pragma unroll
      for (int i = 0; i < 4; ++i) {
        af[i][kk] = *(const bf16x8*)(cur + offA[i][kk]);
        bfr[i][kk] = *(const bf16x8*)(cur + 16384 + offB[i][kk]);
      }
    __builtin_amdgcn_s_setprio(1);
#pragma unroll
    for (int kk = 0; kk < 2; ++kk)
#pragma unroll
      for (int mi = 0; mi < 4; ++mi)
#pragma unroll
        for (int nj = 0; nj < 4; ++nj)
          acc[mi][nj] = __builtin_amdgcn_mfma_f32_16x16x32_bf16(
              af[mi][kk], bfr[nj][kk], acc[mi][nj], 0, 0, 0);
    __builtin_amdgcn_s_setprio(0);
    asm volatile("s_waitcnt vmcnt(0)" ::: "memory");
    __syncthreads();
  }
}

// QKV projection. z=0 -> Q (pre-scaled by 0.125*log2e), z=1 -> K, z=2 -> V^T.
__global__ __launch_bounds__(256) void gemm_qkv_kernel(
    const bf16_t* __restrict__ xb, const bf16_t* __restrict__ qb,
    const bf16_t* __restrict__ Wb, const float* __restrict__ bq,
    const float* __restrict__ bk, const float* __restrict__ bv,
    bf16_t* __restrict__ Qh, bf16_t* __restrict__ Kh, bf16_t* __restrict__ VT) {
  __shared__ char smem[65536];
  const int z = blockIdx.z;
  const bf16_t* A = (z == 0) ? qb : xb;
  const bf16_t* W = Wb + (size_t)z * 262144;
  const float* bias = (z == 0) ? bq : (z == 1) ? bk : bv;

  f32x4 acc[4][4] = {};
  gemm_core(A, W, smem, acc);

  const int lane = threadIdx.x & 63, wid = threadIdx.x >> 6;
  const int wr = wid >> 1, wc = wid & 1;
  const int colbase = blockIdx.x * 128 + wc * 64 + (lane & 15);
  const int rowbase = blockIdx.y * 128 + wr * 64 + ((lane >> 4) << 2);

  if (z == 2) {
#pragma unroll
    for (int nj = 0; nj < 4; ++nj) {
      int c = colbase + nj * 16;
      float bb = bias[c];
      int h = c >> 6, d = c & 63;
#pragma unroll
      for (int mi = 0; mi < 4; ++mi) {
        int r0 = rowbase + mi * 16;
        int b = r0 >> 11, s0 = r0 & 2047;
        bf16x4 v;
#pragma unroll
        for (int rr = 0; rr < 4; ++rr) v[rr] = (bf16_t)(acc[mi][nj][rr] + bb);
        *(bf16x4*)(VT + ((size_t)((b << 3) | h) * 64 + d) * 2048 + s0) = v;
      }
    }
  } else {
    bf16_t* O = (z == 0) ? Qh : Kh;
    const float scl = (z == 0) ? 0.18033688f : 1.0f;  // 0.125 * log2(e)
#pragma unroll
    for (int nj = 0; nj < 4; ++nj) {
      int c = colbase + nj * 16;
      float bb = bias[c];
      int h = c >> 6, d = c & 63;
#pragma unroll
      for (int mi = 0; mi < 4; ++mi)
#pragma unroll
        for (int rr = 0; rr < 4; ++rr) {
          int r = rowbase + mi * 16 + rr;
          int b = r >> 11, s = r & 2047;
          O[((size_t)((b << 3) | h) * 2048 + s) * 64 + d] = (bf16_t)((acc[mi][nj][rr] + bb) * scl);
        }
    }
  }
}

// Output projection: out = ctx @ Wo^T + bo, f32 [8192][512]
__global__ __launch_bounds__(256) void gemm_out_kernel(
    const bf16_t* __restrict__ ctx, const bf16_t* __restrict__ Wo,
    const float* __restrict__ bo, float* __restrict__ out) {
  __shared__ char smem[65536];
  f32x4 acc[4][4] = {};
  gemm_core(ctx, Wo, smem, acc);

  const int lane = threadIdx.x & 63, wid = threadIdx.x >> 6;
  const int wr = wid >> 1, wc = wid & 1;
  const int colbase = blockIdx.x * 128 + wc * 64 + (lane & 15);
  const int rowbase = blockIdx.y * 128 + wr * 64 + ((lane >> 4) << 2);
#pragma unroll
  for (int nj = 0; nj < 4; ++nj) {
    int c = colbase + nj * 16;
    float bb = bo[c];
#pragma unroll
    for (int mi = 0; mi < 4; ++mi)
#pragma unroll
      for (int rr = 0; rr < 4; ++rr) {
        int r = rowbase + mi * 16 + rr;
        out[(size_t)r * 512 + c] = acc[mi][nj][rr] + bb;
      }
  }
}

// ------------- flash attention: swapped 32x32 QK^T, in-register softmax ------
// r5 structure (proven 80us) + XCD swizzle + m_run=0 + 2-shfl exchange.
// grid 512 blocks; remap so all 16 q-tiles of one bh land on one XCD.
__global__ __launch_bounds__(256, 2) void attn_kernel(
    const bf16_t* __restrict__ Qh, const bf16_t* __restrict__ Kh,
    const bf16_t* __restrict__ VT, bf16_t* __restrict__ ctx) {
  __shared__ char smem[32768];
  char* Kb = smem;            // 2 x 8KB: K tile [64 kv][128B d], swizzled
  char* Vb = smem + 16384;    // 2 x 8KB: V^T tile [64 d][128B kv], swizzled
  const int tid = threadIdx.x, lane = tid & 63, wid = tid >> 6;
  const int l31 = lane & 31, h = lane >> 5;
  // XCD-aware remap (T1): bid%8 = XCD; same bh -> same XCD
  const int bid = blockIdx.x + 16 * blockIdx.y;
  const int qt = (bid >> 3) & 15;
  const int bh = (bid & 7) * 4 + (bid >> 7);

  const char* Kbase = (const char*)Kh + (size_t)bh * 262144;  // [2048][128B]
  const char* Vbase = (const char*)VT + (size_t)bh * 262144;  // [64][4096B]
  const char* Qbase = (const char*)Qh + (size_t)bh * 262144;

  // Q fragments (B-operand of swapped QK^T): col=q=lane&31, k=d
  const int qrow = qt * 128 + wid * 32 + l31;
  bf16x8 qf[4];
#pragma unroll
  for (int ks = 0; ks < 4; ++ks)
    qf[ks] = *(const bf16x8*)(Qbase + (size_t)qrow * 128 + ks * 32 + h * 16);

  // staging offsets (4 waves cooperatively stage 8KB K + 8KB V per tile)
  uint32_t kgo[2], vgo[2], lo[2];
#pragma unroll
  for (int c = 0; c < 2; ++c) {
    uint32_t o = (uint32_t)c * 4096u + (uint32_t)wid * 1024u + (uint32_t)lane * 16u;
    uint32_t row = o >> 7;
    uint32_t inner = (o & 127u) ^ ((row & 7u) << 4);
    kgo[c] = row * 128u + inner;   // + t*8192 (K row stride 128B)
    vgo[c] = row * 4096u + inner;  // + t*128  (VT row stride 4096B)
    lo[c] = o - (uint32_t)lane * 16u;
  }

  // fragment read offsets: addr(chunk, ks) = fbase[chunk] + fcol[ks]
  const uint32_t swz = (uint32_t)(l31 & 7) << 4;
  uint32_t fbase[2], fcol[4];
#pragma unroll
  for (int c = 0; c < 2; ++c) fbase[c] = (uint32_t)(32 * c + l31) * 128u;
#pragma unroll
  for (int ks = 0; ks < 4; ++ks) fcol[ks] = ((uint32_t)(ks * 32 + h * 16)) ^ swz;

  f32x16 oacc[2] = {};
  float m_run = 0.0f, l_part = 0.f;  // m=0 valid: defer-check guards overflow

  // prologue: stage tile 0 into buf 0
#pragma unroll
  for (int c = 0; c < 2; ++c) {
    gload_lds16(Kbase + kgo[c], Kb + lo[c]);
    gload_lds16(Vbase + vgo[c], Vb + lo[c]);
  }
  asm volatile("s_waitcnt vmcnt(0)" ::: "memory");
  __syncthreads();

#pragma unroll 1
  for (int t = 0; t < 32; ++t) {
    const uint32_t cur = ((uint32_t)t & 1u) << 13;
    if (t < 31) {
      const uint32_t nxt = cur ^ 8192u;
      const char* Kn = Kbase + (size_t)(t + 1) * 8192;
      const char* Vn = Vbase + (size_t)(t + 1) * 128;
#pragma unroll
      for (int c = 0; c < 2; ++c) {
        gload_lds16(Kn + kgo[c], Kb + nxt + lo[c]);
        gload_lds16(Vn + vgo[c], Vb + nxt + lo[c]);
      }
    }

    // S^T = mfma(K, Q): sT[c][reg] = S[q=l31][kv=32c+(reg&3)+8(reg>>2)+4h]
    f32x16 sT[2] = {};
#pragma unroll
    for (int c = 0; c < 2; ++c) {
      __builtin_amdgcn_s_setprio(1);
#pragma unroll
      for (int ks = 0; ks < 4; ++ks) {
        bf16x8 kf = *(const bf16x8*)(Kb + cur + fbase[c] + fcol[ks]);
        sT[c] = __builtin_amdgcn_mfma_f32_32x32x16_bf16(kf, qf[ks], sT[c], 0, 0, 0);
      }
      __builtin_amdgcn_s_setprio(0);
    }

    // P = exp2(S - m_run) with stale max; defer-check on the P-sum (tree sum)
    uint32_t cw[2][8];
    float la0 = 0.f, la1 = 0.f, la2 = 0.f, la3 = 0.f;
#pragma unroll
    for (int c = 0; c < 2; ++c)
#pragma unroll
      for (int w = 0; w < 8; ++w) {
        float p0 = __builtin_exp2f(sT[c][2 * w] - m_run);
        float p1 = __builtin_exp2f(sT[c][2 * w + 1] - m_run);
        if ((w & 3) == 0) la0 += p0 + p1;
        else if ((w & 3) == 1) la1 += p0 + p1;
        else if ((w & 3) == 2) la2 += p0 + p1;
        else la3 += p0 + p1;
        bf16x2 tp; tp[0] = (bf16_t)p0; tp[1] = (bf16_t)p1;
        cw[c][w] = __builtin_bit_cast(uint32_t, tp);
      }
    float ladd = (la0 + la1) + (la2 + la3);
    if (!__all(ladd <= 16384.0f)) {  // slow path: only on adversarial data
      float mx = sT[0][0];
#pragma unroll
      for (int c = 0; c < 2; ++c)
#pragma unroll
        for (int r = 0; r < 16; ++r) mx = fmaxf(mx, sT[c][r]);
      mx = fmaxf(mx, __shfl_xor(mx, 32));
      float mnew = fmaxf(m_run, mx);
      float sc = __builtin_exp2f(m_run - mnew);
      l_part *= sc;
#pragma unroll
      for (int r = 0; r < 16; ++r) { oacc[0][r] *= sc; oacc[1][r] *= sc; }
      m_run = mnew;
      la0 = la1 = la2 = la3 = 0.f;
#pragma unroll
      for (int c = 0; c < 2; ++c)
#pragma unroll
        for (int w = 0; w < 8; ++w) {
          float p0 = __builtin_exp2f(sT[c][2 * w] - m_run);
          float p1 = __builtin_exp2f(sT[c][2 * w + 1] - m_run);
          if ((w & 3) == 0) la0 += p0 + p1;
          else if ((w & 3) == 1) la1 += p0 + p1;
          else if ((w & 3) == 2) la2 += p0 + p1;
          else la3 += p0 + p1;
          bf16x2 tp; tp[0] = (bf16_t)p0; tp[1] = (bf16_t)p1;
          cw[c][w] = __builtin_bit_cast(uint32_t, tp);
        }
      ladd = (la0 + la1) + (la2 + la3);
    }
    l_part += ladd;

    // exchange (2 shfl per pa[s]): pre-select what the partner needs.
    // h=0 consumes partner's {w0,w1}; h=1 consumes partner's {w2,w3}.
    bf16x8 pa[4];
#pragma unroll
    for (int s = 0; s < 4; ++s) {
      const int c = s >> 1, sp = s & 1;
      uint32_t w0 = cw[c][4 * sp + 0], w1 = cw[c][4 * sp + 1];
      uint32_t w2 = cw[c][4 * sp + 2], w3 = cw[c][4 * sp + 3];
      uint32_t snd0 = h ? w0 : w2;
      uint32_t snd1 = h ? w1 : w3;
      uint32_t rcv0 = (uint32_t)__shfl_xor((int)snd0, 32);
      uint32_t rcv1 = (uint32_t)__shfl_xor((int)snd1, 32);
      u32x4 ta;
      ta[0] = h ? rcv0 : w0;
      ta[1] = h ? rcv1 : w1;
      ta[2] = h ? w2 : rcv0;
      ta[3] = h ? w3 : rcv1;
      pa[s] = __builtin_bit_cast(bf16x8, ta);
    }

    // O^T += mfma(V^T, P^T): oacc[dc] col=q, row d=32dc+(reg&3)+8(reg>>2)+4h
#pragma unroll
    for (int dc = 0; dc < 2; ++dc) {
      __builtin_amdgcn_s_setprio(1);
#pragma unroll
      for (int ks = 0; ks < 4; ++ks) {
        bf16x8 vf = *(const bf16x8*)(Vb + cur + fbase[dc] + fcol[ks]);
        oacc[dc] = __builtin_amdgcn_mfma_f32_32x32x16_bf16(vf, pa[ks], oacc[dc], 0, 0, 0);
      }
      __builtin_amdgcn_s_setprio(0);
    }

    asm volatile("s_waitcnt vmcnt(0)" ::: "memory");
    __syncthreads();
  }

  // epilogue: full row sum = own + partner halves; normalize; write ctx
  float l = l_part + __shfl_xor(l_part, 32);
  float inv = 1.0f / l;
  const int b = bh >> 3, hh = bh & 7;
  bf16_t* crow = ctx + ((size_t)(b * 2048 + qrow)) * 512 + hh * 64;
#pragma unroll
  for (int dc = 0; dc < 2; ++dc)
#pragma unroll
    for (int m = 0; m < 4; ++m) {
      bf16x4 v;
#pragma unroll
      for (int r = 0; r < 4; ++r) v[r] = (bf16_t)(oacc[dc][4 * m + r] * inv);
      *(bf16x4*)(crow + dc * 32 + m * 8 + h * 4) = v;
    }
}

extern "C" void kernel_launch(void* const* d_in, const int* in_sizes, int n_in,
                              void* d_out, int out_size, void* d_ws, size_t ws_size,
                              hipStream_t stream) {
  const float* x  = (const float*)d_in[0];
  const float* q  = (const float*)d_in[1];
  const float* Wq = (const float*)d_in[2];
  const float* bq = (const float*)d_in[3];
  const float* Wk = (const float*)d_in[4];
  const float* bk = (const float*)d_in[5];
  const float* Wv = (const float*)d_in[6];
  const float* bv = (const float*)d_in[7];
  const float* Wo = (const float*)d_in[8];
  const float* bo = (const float*)d_in[9];

  char* ws = (char*)d_ws;
  bf16_t* xb  = (bf16_t*)(ws + 0);          // 8 MB
  bf16_t* qb  = (bf16_t*)(ws + 8388608);    // 8 MB
  bf16_t* Wb  = (bf16_t*)(ws + 16777216);   // 4 x 512KB
  bf16_t* Qh  = (bf16_t*)(ws + 18874368);   // 8 MB [32][2048][64]
  bf16_t* Kh  = (bf16_t*)(ws + 27262976);   // 8 MB [32][2048][64]
  bf16_t* VT  = (bf16_t*)(ws + 35651584);   // 8 MB [32][64][2048]
  bf16_t* ctx = (bf16_t*)(ws + 44040192);   // 8 MB

  cvt_all_kernel<<<dim3(2048, 3), 256, 0, stream>>>(x, q, Wq, Wk, Wv, Wo, xb, qb, Wb);
  gemm_qkv_kernel<<<dim3(4, 64, 3), 256, 0, stream>>>(xb, qb, Wb, bq, bk, bv, Qh, Kh, VT);
  attn_kernel<<<dim3(16, 32), 256, 0, stream>>>(Qh, Kh, VT, ctx);
  gemm_out_kernel<<<dim3(4, 64), 256, 0, stream>>>(ctx, Wb + 3 * 262144, bo, (float*)d_out);
}

// Round 10
// 116.091 us; speedup vs baseline: 2.5639x; 1.0107x over previous
//
#include <hip/hip_runtime.h>
#include <stdint.h>

typedef __bf16 bf16_t;
typedef bf16_t bf16x8 __attribute__((ext_vector_type(8)));
typedef bf16_t bf16x4 __attribute__((ext_vector_type(4)));
typedef bf16_t bf16x2 __attribute__((ext_vector_type(2)));
typedef float f32x4 __attribute__((ext_vector_type(4)));
typedef float f32x16 __attribute__((ext_vector_type(16)));
typedef uint32_t u32x4 __attribute__((ext_vector_type(4)));

#define DEV __device__ __forceinline__

DEV void gload_lds16(const void* g, void* l) {
  __builtin_amdgcn_global_load_lds(
      (__attribute__((address_space(1))) void*)(g),
      (__attribute__((address_space(3))) void*)(l), 16, 0, 0);
}

// ---------------- fused convert kernel (x, q, 4 weights) ----------------
__global__ __launch_bounds__(256) void cvt_all_kernel(
    const float* __restrict__ x, const float* __restrict__ q,
    const float* __restrict__ Wq, const float* __restrict__ Wk,
    const float* __restrict__ Wv, const float* __restrict__ Wo,
    bf16_t* __restrict__ xb, bf16_t* __restrict__ qb, bf16_t* __restrict__ Wb) {
  const int y = blockIdx.y;
  int i = blockIdx.x * 256 + threadIdx.x;
  const float* s;
  bf16_t* d;
  if (y == 0) { s = x; d = xb; }
  else if (y == 1) { s = q; d = qb; }
  else {
    if (i >= 131072) return;
    int widx = i >> 15;
    s = (widx == 0) ? Wq : (widx == 1) ? Wk : (widx == 2) ? Wv : Wo;
    d = Wb + (size_t)widx * 262144;
    i &= 32767;
  }
  const float4* sp = (const float4*)s + (size_t)i * 2;
  float4 a = sp[0], b = sp[1];
  bf16x8 o;
  o[0] = (bf16_t)a.x; o[1] = (bf16_t)a.y; o[2] = (bf16_t)a.z; o[3] = (bf16_t)a.w;
  o[4] = (bf16_t)b.x; o[5] = (bf16_t)b.y; o[6] = (bf16_t)b.z; o[7] = (bf16_t)b.w;
  *(bf16x8*)(d + (size_t)i * 8) = o;
}

// ---------------- GEMM core: C[128x128] = A[128xK] * W[128xK]^T ----------------
DEV void gemm_core(const bf16_t* __restrict__ A, const bf16_t* __restrict__ W,
                   char* smem, f32x4 (&acc)[4][4]) {
  const int tid = threadIdx.x;
  const int lane = tid & 63;
  const int wid = tid >> 6;
  const int wr = wid >> 1, wc = wid & 1;
  const int bx = blockIdx.x, by = blockIdx.y;

  uint32_t goffA[4], goffB[4], ldsoff[4];
#pragma unroll
  for (int c = 0; c < 4; ++c) {
    uint32_t o = (uint32_t)wid * 4096u + (uint32_t)c * 1024u + (uint32_t)lane * 16u;
    uint32_t row = o >> 7;
    uint32_t inner = (o & 127u) ^ ((row & 7u) << 4);
    goffA[c] = ((uint32_t)by * 128u + row) * 1024u + inner;
    goffB[c] = ((uint32_t)bx * 128u + row) * 1024u + inner;
    ldsoff[c] = o - (uint32_t)lane * 16u;
  }
  uint32_t offA[4][2], offB[4][2];
#pragma unroll
  for (int i = 0; i < 4; ++i)
#pragma unroll
    for (int kk = 0; kk < 2; ++kk) {
      uint32_t ra = (uint32_t)(wr * 64 + i * 16 + (lane & 15));
      offA[i][kk] = ra * 128u + (((uint32_t)kk * 64u + ((lane >> 4) * 16u)) ^ ((ra & 7u) << 4));
      uint32_t rb = (uint32_t)(wc * 64 + i * 16 + (lane & 15));
      offB[i][kk] = rb * 128u + (((uint32_t)kk * 64u + ((lane >> 4) * 16u)) ^ ((rb & 7u) << 4));
    }

  const char* Ab = (const char*)A;
  const char* Wb = (const char*)W;

#pragma unroll
  for (int c = 0; c < 4; ++c) {
    gload_lds16(Ab + goffA[c], smem + ldsoff[c]);
    gload_lds16(Wb + goffB[c], smem + 16384 + ldsoff[c]);
  }
  asm volatile("s_waitcnt vmcnt(0)" ::: "memory");
  __syncthreads();

#pragma unroll 1
  for (int kt = 0; kt < 8; ++kt) {
    const int buf = kt & 1;
    char* cur = smem + buf * 32768;
    if (kt < 7) {
      char* nxt = smem + (buf ^ 1) * 32768;
      uint32_t gk = (uint32_t)(kt + 1) * 128u;
#pragma unroll
      for (int c = 0; c < 4; ++c) {
        gload_lds16(Ab + goffA[c] + gk, nxt + ldsoff[c]);
        gload_lds16(Wb + goffB[c] + gk, nxt + 16384 + ldsoff[c]);
      }
    }
    bf16x8 af[4][2], bfr[4][2];
#pragma unroll
    for (int kk = 0; kk < 2; ++kk)
#pragma unroll
      for (int i = 0; i < 4; ++i) {
        af[i][kk] = *(const bf16x8*)(cur + offA[i][kk]);
        bfr[i][kk] = *(const bf16x8*)(cur + 16384 + offB[i][kk]);
      }
    __builtin_amdgcn_s_setprio(1);
#pragma unroll
    for (int kk = 0; kk < 2; ++kk)
#pragma unroll
      for (int mi = 0; mi < 4; ++mi)
#pragma unroll
        for (int nj = 0; nj < 4; ++nj)
          acc[mi][nj] = __builtin_amdgcn_mfma_f32_16x16x32_bf16(
              af[mi][kk], bfr[nj][kk], acc[mi][nj], 0, 0, 0);
    __builtin_amdgcn_s_setprio(0);
    asm volatile("s_waitcnt vmcnt(0)" ::: "memory");
    __syncthreads();
  }
}

// QKV projection. z=0 -> Q (pre-scaled by 0.125*log2e), z=1 -> K, z=2 -> V^T.
__global__ __launch_bounds__(256) void gemm_qkv_kernel(
    const bf16_t* __restrict__ xb, const bf16_t* __restrict__ qb,
    const bf16_t* __restrict__ Wb, const float* __restrict__ bq,
    const float* __restrict__ bk, const float* __restrict__ bv,
    bf16_t* __restrict__ Qh, bf16_t* __restrict__ Kh, bf16_t* __restrict__ VT) {
  __shared__ char smem[65536];
  const int z = blockIdx.z;
  const bf16_t* A = (z == 0) ? qb : xb;
  const bf16_t* W = Wb + (size_t)z * 262144;
  const float* bias = (z == 0) ? bq : (z == 1) ? bk : bv;

  f32x4 acc[4][4] = {};
  gemm_core(A, W, smem, acc);

  const int lane = threadIdx.x & 63, wid = threadIdx.x >> 6;
  const int wr = wid >> 1, wc = wid & 1;
  const int colbase = blockIdx.x * 128 + wc * 64 + (lane & 15);
  const int rowbase = blockIdx.y * 128 + wr * 64 + ((lane >> 4) << 2);

  if (z == 2) {
#pragma unroll
    for (int nj = 0; nj < 4; ++nj) {
      int c = colbase + nj * 16;
      float bb = bias[c];
      int h = c >> 6, d = c & 63;
#pragma unroll
      for (int mi = 0; mi < 4; ++mi) {
        int r0 = rowbase + mi * 16;
        int b = r0 >> 11, s0 = r0 & 2047;
        bf16x4 v;
#pragma unroll
        for (int rr = 0; rr < 4; ++rr) v[rr] = (bf16_t)(acc[mi][nj][rr] + bb);
        *(bf16x4*)(VT + ((size_t)((b << 3) | h) * 64 + d) * 2048 + s0) = v;
      }
    }
  } else {
    bf16_t* O = (z == 0) ? Qh : Kh;
    const float scl = (z == 0) ? 0.18033688f : 1.0f;  // 0.125 * log2(e)
#pragma unroll
    for (int nj = 0; nj < 4; ++nj) {
      int c = colbase + nj * 16;
      float bb = bias[c];
      int h = c >> 6, d = c & 63;
#pragma unroll
      for (int mi = 0; mi < 4; ++mi)
#pragma unroll
        for (int rr = 0; rr < 4; ++rr) {
          int r = rowbase + mi * 16 + rr;
          int b = r >> 11, s = r & 2047;
          O[((size_t)((b << 3) | h) * 2048 + s) * 64 + d] = (bf16_t)((acc[mi][nj][rr] + bb) * scl);
        }
    }
  }
}

// Output projection: out = ctx @ Wo^T + bo, f32 [8192][512]
__global__ __launch_bounds__(256) void gemm_out_kernel(
    const bf16_t* __restrict__ ctx, const bf16_t* __restrict__ Wo,
    const float* __restrict__ bo, float* __restrict__ out) {
  __shared__ char smem[65536];
  f32x4 acc[4][4] = {};
  gemm_core(ctx, Wo, smem, acc);

  const int lane = threadIdx.x & 63, wid = threadIdx.x >> 6;
  const int wr = wid >> 1, wc = wid & 1;
  const int colbase = blockIdx.x * 128 + wc * 64 + (lane & 15);
  const int rowbase = blockIdx.y * 128 + wr * 64 + ((lane >> 4) << 2);
#pragma unroll
  for (int nj = 0; nj < 4; ++nj) {
    int c = colbase + nj * 16;
    float bb = bo[c];
#pragma unroll
    for (int mi = 0; mi < 4; ++mi)
#pragma unroll
      for (int rr = 0; rr < 4; ++rr) {
        int r = rowbase + mi * 16 + rr;
        out[(size_t)r * 512 + c] = acc[mi][nj][rr] + bb;
      }
  }
}

// ------------- flash attention: swapped 32x32 QK^T, 2-tile epochs ------------
// r9 structure with 4 LDS buffers; one vmcnt(0)+barrier per 2 KV tiles.
__global__ __launch_bounds__(256, 2) void attn_kernel(
    const bf16_t* __restrict__ Qh, const bf16_t* __restrict__ Kh,
    const bf16_t* __restrict__ VT, bf16_t* __restrict__ ctx) {
  __shared__ char smem[65536];  // K bufs: 4 x 8KB @ 0; V bufs: 4 x 8KB @ 32768
  const int tid = threadIdx.x, lane = tid & 63, wid = tid >> 6;
  const int l31 = lane & 31, h = lane >> 5;
  // XCD-aware remap (T1): bid%8 = XCD; same bh -> same XCD
  const int bid = blockIdx.x + 16 * blockIdx.y;
  const int qt = (bid >> 3) & 15;
  const int bh = (bid & 7) * 4 + (bid >> 7);

  const char* Kbase = (const char*)Kh + (size_t)bh * 262144;  // [2048][128B]
  const char* Vbase = (const char*)VT + (size_t)bh * 262144;  // [64][4096B]
  const char* Qbase = (const char*)Qh + (size_t)bh * 262144;

  // Q fragments (B-operand of swapped QK^T): col=q=lane&31, k=d
  const int qrow = qt * 128 + wid * 32 + l31;
  bf16x8 qf[4];
#pragma unroll
  for (int ks = 0; ks < 4; ++ks)
    qf[ks] = *(const bf16x8*)(Qbase + (size_t)qrow * 128 + ks * 32 + h * 16);

  // staging offsets (4 waves cooperatively stage 8KB K + 8KB V per tile)
  uint32_t kgo[2], vgo[2], lo[2];
#pragma unroll
  for (int c = 0; c < 2; ++c) {
    uint32_t o = (uint32_t)c * 4096u + (uint32_t)wid * 1024u + (uint32_t)lane * 16u;
    uint32_t row = o >> 7;
    uint32_t inner = (o & 127u) ^ ((row & 7u) << 4);
    kgo[c] = row * 128u + inner;   // + t*8192 (K row stride 128B)
    vgo[c] = row * 4096u + inner;  // + t*128  (VT row stride 4096B)
    lo[c] = o - (uint32_t)lane * 16u;
  }

  // fragment read offsets
  const uint32_t swz = (uint32_t)(l31 & 7) << 4;
  uint32_t fbase[2], fcol[4];
#pragma unroll
  for (int c = 0; c < 2; ++c) fbase[c] = (uint32_t)(32 * c + l31) * 128u;
#pragma unroll
  for (int ks = 0; ks < 4; ++ks) fcol[ks] = ((uint32_t)(ks * 32 + h * 16)) ^ swz;

  f32x16 oacc[2] = {};
  float m_run = 0.0f, l_part = 0.f;  // m=0 valid: defer-check guards overflow

  // prologue: stage tiles 0,1 into bufs 0,1
#pragma unroll
  for (int tt = 0; tt < 2; ++tt) {
    const char* Kt = Kbase + (size_t)tt * 8192;
    const char* Vt = Vbase + (size_t)tt * 128;
#pragma unroll
    for (int c = 0; c < 2; ++c) {
      gload_lds16(Kt + kgo[c], smem + tt * 8192 + lo[c]);
      gload_lds16(Vt + vgo[c], smem + 32768 + tt * 8192 + lo[c]);
    }
  }
  asm volatile("s_waitcnt vmcnt(0)" ::: "memory");
  __syncthreads();

#pragma unroll 1
  for (int te = 0; te < 16; ++te) {
    const int t0 = te * 2;
    // stage next epoch's two tiles into the two buffers not in use
    if (t0 < 30) {
#pragma unroll
      for (int j = 2; j < 4; ++j) {
        const int tn = t0 + j;
        const uint32_t nb = ((uint32_t)tn & 3u) * 8192u;
        const char* Kn = Kbase + (size_t)tn * 8192;
        const char* Vn = Vbase + (size_t)tn * 128;
#pragma unroll
        for (int c = 0; c < 2; ++c) {
          gload_lds16(Kn + kgo[c], smem + nb + lo[c]);
          gload_lds16(Vn + vgo[c], smem + 32768 + nb + lo[c]);
        }
      }
    }

    // compute the epoch's two tiles
#pragma unroll
    for (int j = 0; j < 2; ++j) {
      const uint32_t cur = ((uint32_t)(t0 + j) & 3u) * 8192u;
      const char* Kc = smem + cur;
      const char* Vc = smem + 32768 + cur;

      // S^T = mfma(K, Q): sT[c][reg] = S[q=l31][kv=32c+(reg&3)+8(reg>>2)+4h]
      f32x16 sT[2] = {};
#pragma unroll
      for (int c = 0; c < 2; ++c) {
        __builtin_amdgcn_s_setprio(1);
#pragma unroll
        for (int ks = 0; ks < 4; ++ks) {
          bf16x8 kf = *(const bf16x8*)(Kc + fbase[c] + fcol[ks]);
          sT[c] = __builtin_amdgcn_mfma_f32_32x32x16_bf16(kf, qf[ks], sT[c], 0, 0, 0);
        }
        __builtin_amdgcn_s_setprio(0);
      }

      // P = exp2(S - m_run) with stale max; defer-check on the P-sum
      uint32_t cw[2][8];
      float la0 = 0.f, la1 = 0.f, la2 = 0.f, la3 = 0.f;
#pragma unroll
      for (int c = 0; c < 2; ++c)
#pragma unroll
        for (int w = 0; w < 8; ++w) {
          float p0 = __builtin_exp2f(sT[c][2 * w] - m_run);
          float p1 = __builtin_exp2f(sT[c][2 * w + 1] - m_run);
          if ((w & 3) == 0) la0 += p0 + p1;
          else if ((w & 3) == 1) la1 += p0 + p1;
          else if ((w & 3) == 2) la2 += p0 + p1;
          else la3 += p0 + p1;
          bf16x2 tp; tp[0] = (bf16_t)p0; tp[1] = (bf16_t)p1;
          cw[c][w] = __builtin_bit_cast(uint32_t, tp);
        }
      float ladd = (la0 + la1) + (la2 + la3);
      if (!__all(ladd <= 16384.0f)) {  // slow path: only on adversarial data
        float mx = sT[0][0];
#pragma unroll
        for (int c = 0; c < 2; ++c)
#pragma unroll
          for (int r = 0; r < 16; ++r) mx = fmaxf(mx, sT[c][r]);
        mx = fmaxf(mx, __shfl_xor(mx, 32));
        float mnew = fmaxf(m_run, mx);
        float sc = __builtin_exp2f(m_run - mnew);
        l_part *= sc;
#pragma unroll
        for (int r = 0; r < 16; ++r) { oacc[0][r] *= sc; oacc[1][r] *= sc; }
        m_run = mnew;
        la0 = la1 = la2 = la3 = 0.f;
#pragma unroll
        for (int c = 0; c < 2; ++c)
#pragma unroll
          for (int w = 0; w < 8; ++w) {
            float p0 = __builtin_exp2f(sT[c][2 * w] - m_run);
            float p1 = __builtin_exp2f(sT[c][2 * w + 1] - m_run);
            if ((w & 3) == 0) la0 += p0 + p1;
            else if ((w & 3) == 1) la1 += p0 + p1;
            else if ((w & 3) == 2) la2 += p0 + p1;
            else la3 += p0 + p1;
            bf16x2 tp; tp[0] = (bf16_t)p0; tp[1] = (bf16_t)p1;
            cw[c][w] = __builtin_bit_cast(uint32_t, tp);
          }
        ladd = (la0 + la1) + (la2 + la3);
      }
      l_part += ladd;

      // exchange (2 shfl per pa[s]): pre-select what the partner needs.
      bf16x8 pa[4];
#pragma unroll
      for (int s = 0; s < 4; ++s) {
        const int c = s >> 1, sp = s & 1;
        uint32_t w0 = cw[c][4 * sp + 0], w1 = cw[c][4 * sp + 1];
        uint32_t w2 = cw[c][4 * sp + 2], w3 = cw[c][4 * sp + 3];
        uint32_t snd0 = h ? w0 : w2;
        uint32_t snd1 = h ? w1 : w3;
        uint32_t rcv0 = (uint32_t)__shfl_xor((int)snd0, 32);
        uint32_t rcv1 = (uint32_t)__shfl_xor((int)snd1, 32);
        u32x4 ta;
        ta[0] = h ? rcv0 : w0;
        ta[1] = h ? rcv1 : w1;
        ta[2] = h ? w2 : rcv0;
        ta[3] = h ? w3 : rcv1;
        pa[s] = __builtin_bit_cast(bf16x8, ta);
      }

      // O^T += mfma(V^T, P^T)
#pragma unroll
      for (int dc = 0; dc < 2; ++dc) {
        __builtin_amdgcn_s_setprio(1);
#pragma unroll
        for (int ks = 0; ks < 4; ++ks) {
          bf16x8 vf = *(const bf16x8*)(Vc + fbase[dc] + fcol[ks]);
          oacc[dc] = __builtin_amdgcn_mfma_f32_32x32x16_bf16(vf, pa[ks], oacc[dc], 0, 0, 0);
        }
        __builtin_amdgcn_s_setprio(0);
      }
    }

    // single drain + barrier per epoch (2 tiles)
    asm volatile("s_waitcnt vmcnt(0)" ::: "memory");
    __syncthreads();
  }

  // epilogue: full row sum = own + partner halves; normalize; write ctx
  float l = l_part + __shfl_xor(l_part, 32);
  float inv = 1.0f / l;
  const int b = bh >> 3, hh = bh & 7;
  bf16_t* crow = ctx + ((size_t)(b * 2048 + qrow)) * 512 + hh * 64;
#pragma unroll
  for (int dc = 0; dc < 2; ++dc)
#pragma unroll
    for (int m = 0; m < 4; ++m) {
      bf16x4 v;
#pragma unroll
      for (int r = 0; r < 4; ++r) v[r] = (bf16_t)(oacc[dc][4 * m + r] * inv);
      *(bf16x4*)(crow + dc * 32 + m * 8 + h * 4) = v;
    }
}

extern "C" void kernel_launch(void* const* d_in, const int* in_sizes, int n_in,
                              void* d_out, int out_size, void* d_ws, size_t ws_size,
                              hipStream_t stream) {
  const float* x  = (const float*)d_in[0];
  const float* q  = (const float*)d_in[1];
  const float* Wq = (const float*)d_in[2];
  const float* bq = (const float*)d_in[3];
  const float* Wk = (const float*)d_in[4];
  const float* bk = (const float*)d_in[5];
  const float* Wv = (const float*)d_in[6];
  const float* bv = (const float*)d_in[7];
  const float* Wo = (const float*)d_in[8];
  const float* bo = (const float*)d_in[9];

  char* ws = (char*)d_ws;
  bf16_t* xb  = (bf16_t*)(ws + 0);          // 8 MB
  bf16_t* qb  = (bf16_t*)(ws + 8388608);    // 8 MB
  bf16_t* Wb  = (bf16_t*)(ws + 16777216);   // 4 x 512KB
  bf16_t* Qh  = (bf16_t*)(ws + 18874368);   // 8 MB [32][2048][64]
  bf16_t* Kh  = (bf16_t*)(ws + 27262976);   // 8 MB [32][2048][64]
  bf16_t* VT  = (bf16_t*)(ws + 35651584);   // 8 MB [32][64][2048]
  bf16_t* ctx = (bf16_t*)(ws + 44040192);   // 8 MB

  cvt_all_kernel<<<dim3(2048, 3), 256, 0, stream>>>(x, q, Wq, Wk, Wv, Wo, xb, qb, Wb);
  gemm_qkv_kernel<<<dim3(4, 64, 3), 256, 0, stream>>>(xb, qb, Wb, bq, bk, bv, Qh, Kh, VT);
  attn_kernel<<<dim3(16, 32), 256, 0, stream>>>(Qh, Kh, VT, ctx);
  gemm_out_kernel<<<dim3(4, 64), 256, 0, stream>>>(ctx, Wb + 3 * 262144, bo, (float*)d_out);
}